// Round 2
// baseline (1191.916 us; speedup 1.0000x reference)
//
#include <hip/hip_runtime.h>
#include <hip/hip_bf16.h>
#include <stdint.h>

#define NNODES 100000
#define NEDGES 1600000
#define C2 128
#define EFEAT 32
#define BN_EPS 1e-5f
#define CH 32

typedef __hip_bfloat16 bf16;

__device__ __forceinline__ float bflo(uint32_t u) { return __uint_as_float(u << 16); }
__device__ __forceinline__ float bfhi(uint32_t u) { return __uint_as_float(u & 0xffff0000u); }
__device__ __forceinline__ float sigm(float x) { return 1.0f / (1.0f + __expf(-x)); }
__device__ __forceinline__ float softp(float x) { return fmaxf(x, 0.0f) + log1pf(__expf(-fabsf(x))); }

struct TB {};  // tensors are bf16
struct TF {};  // tensors are fp32

template <class T> struct LD;
template <> struct LD<TB> {
    static __device__ __forceinline__ float ld(const void* p, size_t i) {
        return __bfloat162float(((const bf16*)p)[i]);
    }
    static __device__ __forceinline__ float2 ld2(const void* p, size_t i) {
        const uint32_t u = *(const uint32_t*)((const bf16*)p + i);
        return make_float2(bflo(u), bfhi(u));
    }
    static __device__ __forceinline__ float4 ld4(const void* p, size_t i) {
        const uint2 v = *(const uint2*)((const bf16*)p + i);
        return make_float4(bflo(v.x), bfhi(v.x), bflo(v.y), bfhi(v.y));
    }
    static __device__ __forceinline__ void st2(void* p, size_t i, float a, float b) {
        union { bf16 h[2]; uint32_t u; } pk;
        pk.h[0] = __float2bfloat16(a);
        pk.h[1] = __float2bfloat16(b);
        *(uint32_t*)((bf16*)p + i) = pk.u;
    }
};
template <> struct LD<TF> {
    static __device__ __forceinline__ float ld(const void* p, size_t i) {
        return ((const float*)p)[i];
    }
    static __device__ __forceinline__ float2 ld2(const void* p, size_t i) {
        return *(const float2*)((const float*)p + i);
    }
    static __device__ __forceinline__ float4 ld4(const void* p, size_t i) {
        return *(const float4*)((const float*)p + i);
    }
    static __device__ __forceinline__ void st2(void* p, size_t i, float a, float b) {
        *(float2*)((float*)p + i) = make_float2(a, b);
    }
};

// K0: detect dtype. fp32 data read as packed bf16 has huge low-half values.
__global__ void k_detect(const uint32_t* __restrict__ nodeb, int* __restrict__ flag) {
    __shared__ int sfp;
    if (threadIdx.x == 0) sfp = 0;
    __syncthreads();
    const float v = fabsf(bflo(nodeb[threadIdx.x]));
    if (v > 1e10f) sfp = 1;
    __syncthreads();
    if (threadIdx.x == 0) *flag = sfp;
}

// ---------------- K1: per-node tables -----------------------------------
// h_src = node@Wsrc+bsrc, h_dst = node@Wdst+bdst; stored bf16 pair-interleaved:
// dword j of a row = (col j | col j+64 << 16)
template <class T>
__device__ __forceinline__ void tables_body(
    const void* node, const void* Wsrc, const void* bsrc,
    const void* Wdst, const void* bdst, bf16* tsrc, bf16* tdst, float* x)
{
    const int t = threadIdx.x;
    const int col = t & 127;
    const void* W = (t < 128) ? Wsrc : Wdst;
    float w[64];
#pragma unroll
    for (int k = 0; k < 64; ++k) w[k] = LD<T>::ld(W, k * C2 + col);
    const float b = (t < 128) ? LD<T>::ld(bsrc, col) : LD<T>::ld(bdst, col);
    bf16* tab = (t < 128) ? tsrc : tdst;
    const int pos = (col < 64) ? (2 * col) : (2 * col - 127);
    for (int base = blockIdx.x * 4; base < NNODES; base += gridDim.x * 4) {
        x[t] = LD<T>::ld(node, (size_t)base * 64 + t);
        __syncthreads();
        float a0 = b, a1 = b, a2 = b, a3 = b;
#pragma unroll
        for (int k = 0; k < 64; ++k) {
            const float wv = w[k];
            a0 = fmaf(x[k], wv, a0);
            a1 = fmaf(x[64 + k], wv, a1);
            a2 = fmaf(x[128 + k], wv, a2);
            a3 = fmaf(x[192 + k], wv, a3);
        }
        __syncthreads();
        tab[(size_t)(base + 0) * C2 + pos] = __float2bfloat16(a0);
        tab[(size_t)(base + 1) * C2 + pos] = __float2bfloat16(a1);
        tab[(size_t)(base + 2) * C2 + pos] = __float2bfloat16(a2);
        tab[(size_t)(base + 3) * C2 + pos] = __float2bfloat16(a3);
    }
}

__global__ __launch_bounds__(256) void k_tables(
    const void* node, const void* Wsrc, const void* bsrc,
    const void* Wdst, const void* bdst, bf16* tsrc, bf16* tdst, const int* flag)
{
    __shared__ float x[256];
    if (*flag) tables_body<TF>(node, Wsrc, bsrc, Wdst, bdst, tsrc, tdst, x);
    else       tables_body<TB>(node, Wsrc, bsrc, Wdst, bdst, tsrc, tdst, x);
}

// ---------------- K2: edge stats ----------------------------------------
template <class T>
__device__ __forceinline__ void edge_stats_body(
    const void* ef, const int* src, const int* dst, const void* We, const void* be,
    const uint32_t* tsrc, const uint32_t* tdst, float* mstats,
    float* efb, int* sidx, int* didx, float* red)
{
    const int t = threadIdx.x;
    const int c = t & 63;
    const int eg = t >> 6;
    float w0[EFEAT], w1[EFEAT];
#pragma unroll
    for (int k = 0; k < EFEAT; ++k) {
        w0[k] = LD<T>::ld(We, k * C2 + c);
        w1[k] = LD<T>::ld(We, k * C2 + c + 64);
    }
    const float be0 = LD<T>::ld(be, c), be1 = LD<T>::ld(be, c + 64);
    float s0 = 0.f, q0 = 0.f, s1 = 0.f, q1 = 0.f;
    for (int chunk = blockIdx.x * CH; chunk < NEDGES; chunk += gridDim.x * CH) {
        ((float4*)efb)[t] = LD<T>::ld4(ef, (size_t)chunk * EFEAT + 4 * t);
        if (t < CH) sidx[t] = src[chunk + t];
        else if (t < 2 * CH) didx[t - CH] = dst[chunk + t - CH];
        __syncthreads();
        for (int e0 = 0; e0 < CH; e0 += 4) {
            const int e = e0 + eg;
            const int s = sidx[e], d = didx[e];
            float el0 = be0, el1 = be1;
            const float4* efv = (const float4*)(efb + e * EFEAT);
#pragma unroll
            for (int k4 = 0; k4 < EFEAT / 4; ++k4) {
                const float4 f = efv[k4];
                el0 = fmaf(f.x, w0[4 * k4 + 0], el0); el1 = fmaf(f.x, w1[4 * k4 + 0], el1);
                el0 = fmaf(f.y, w0[4 * k4 + 1], el0); el1 = fmaf(f.y, w1[4 * k4 + 1], el1);
                el0 = fmaf(f.z, w0[4 * k4 + 2], el0); el1 = fmaf(f.z, w1[4 * k4 + 2], el1);
                el0 = fmaf(f.w, w0[4 * k4 + 3], el0); el1 = fmaf(f.w, w1[4 * k4 + 3], el1);
            }
            const uint32_t us = tsrc[(size_t)s * 64 + c];
            const uint32_t ud = tdst[(size_t)d * 64 + c];
            const float m0 = el0 + bflo(us) + bflo(ud);
            const float m1 = el1 + bfhi(us) + bfhi(ud);
            s0 += m0; q0 += m0 * m0;
            s1 += m1; q1 += m1 * m1;
        }
        __syncthreads();
    }
    ((float4*)red)[t] = make_float4(s0, q0, s1, q1);
    __syncthreads();
    if (t < 64) {
        float a0 = 0.f, a1 = 0.f, a2 = 0.f, a3 = 0.f;
        for (int g = 0; g < 4; ++g) {
            const float4 r = ((const float4*)red)[g * 64 + t];
            a0 += r.x; a1 += r.y; a2 += r.z; a3 += r.w;
        }
        atomicAdd(&mstats[t], a0);
        atomicAdd(&mstats[C2 + t], a1);
        atomicAdd(&mstats[t + 64], a2);
        atomicAdd(&mstats[C2 + t + 64], a3);
    }
}

__global__ __launch_bounds__(256) void k_edge_stats(
    const void* ef, const int* src, const int* dst, const void* We, const void* be,
    const uint32_t* tsrc, const uint32_t* tdst, float* mstats, const int* flag)
{
    __shared__ float efb[CH * EFEAT];
    __shared__ int sidx[CH], didx[CH];
    __shared__ float red[1024];
    if (*flag) edge_stats_body<TF>(ef, src, dst, We, be, tsrc, tdst, mstats, efb, sidx, didx, red);
    else       edge_stats_body<TB>(ef, src, dst, We, be, tsrc, tdst, mstats, efb, sidx, didx, red);
}

// ---------------- K3: finalize m-BN -------------------------------------
template <class T>
__device__ __forceinline__ void fin_m_body(const float* mstats, const void* gamma,
                                           const void* beta, float* mss)
{
    const int c = threadIdx.x;  // 128
    const float inv = 1.0f / (float)NEDGES;
    const float mean = mstats[c] * inv;
    const float var = fmaxf(mstats[C2 + c] * inv - mean * mean, 0.0f);
    const float sc = LD<T>::ld(gamma, c) * rsqrtf(var + BN_EPS);
    mss[c] = sc;
    mss[C2 + c] = LD<T>::ld(beta, c) - mean * sc;
}

__global__ void k_fin_m(const float* mstats, const void* gamma, const void* beta,
                        float* mss, const int* flag)
{
    if (*flag) fin_m_body<TF>(mstats, gamma, beta, mss);
    else       fin_m_body<TB>(mstats, gamma, beta, mss);
}

// ---------------- K4: edge apply (gate + scatter) ------------------------
template <class T>
__device__ __forceinline__ void edge_apply_body(
    const void* ef, const int* src, const int* dst, const void* We, const void* be,
    const uint32_t* tsrc, const uint32_t* tdst, const float* mss, float* hacc,
    float* efb, int* sidx, int* didx)
{
    const int t = threadIdx.x;
    const int c = t & 63;
    const int eg = t >> 6;
    float w0[EFEAT], w1[EFEAT];
#pragma unroll
    for (int k = 0; k < EFEAT; ++k) {
        w0[k] = LD<T>::ld(We, k * C2 + c);
        w1[k] = LD<T>::ld(We, k * C2 + c + 64);
    }
    const float be0 = LD<T>::ld(be, c), be1 = LD<T>::ld(be, c + 64);
    const float sc0 = mss[c], sh0 = mss[C2 + c];
    const float sc1 = mss[c + 64], sh1 = mss[C2 + c + 64];
    for (int chunk = blockIdx.x * CH; chunk < NEDGES; chunk += gridDim.x * CH) {
        ((float4*)efb)[t] = LD<T>::ld4(ef, (size_t)chunk * EFEAT + 4 * t);
        if (t < CH) sidx[t] = src[chunk + t];
        else if (t < 2 * CH) didx[t - CH] = dst[chunk + t - CH];
        __syncthreads();
        for (int e0 = 0; e0 < CH; e0 += 4) {
            const int e = e0 + eg;
            const int s = sidx[e], d = didx[e];
            float el0 = be0, el1 = be1;
            const float4* efv = (const float4*)(efb + e * EFEAT);
#pragma unroll
            for (int k4 = 0; k4 < EFEAT / 4; ++k4) {
                const float4 f = efv[k4];
                el0 = fmaf(f.x, w0[4 * k4 + 0], el0); el1 = fmaf(f.x, w1[4 * k4 + 0], el1);
                el0 = fmaf(f.y, w0[4 * k4 + 1], el0); el1 = fmaf(f.y, w1[4 * k4 + 1], el1);
                el0 = fmaf(f.z, w0[4 * k4 + 2], el0); el1 = fmaf(f.z, w1[4 * k4 + 2], el1);
                el0 = fmaf(f.w, w0[4 * k4 + 3], el0); el1 = fmaf(f.w, w1[4 * k4 + 3], el1);
            }
            const uint32_t us = tsrc[(size_t)s * 64 + c];
            const uint32_t ud = tdst[(size_t)d * 64 + c];
            const float m0 = el0 + bflo(us) + bflo(ud);
            const float m1 = el1 + bfhi(us) + bfhi(ud);
            const float g = sigm(fmaf(m0, sc0, sh0)) * softp(fmaf(m1, sc1, sh1));
            atomicAdd(&hacc[(size_t)d * 64 + c], g);
        }
        __syncthreads();
    }
}

__global__ __launch_bounds__(256) void k_edge_apply(
    const void* ef, const int* src, const int* dst, const void* We, const void* be,
    const uint32_t* tsrc, const uint32_t* tdst, const float* mss, float* hacc,
    const int* flag)
{
    __shared__ float efb[CH * EFEAT];
    __shared__ int sidx[CH], didx[CH];
    if (*flag) edge_apply_body<TF>(ef, src, dst, We, be, tsrc, tdst, mss, hacc, efb, sidx, didx);
    else       edge_apply_body<TB>(ef, src, dst, We, be, tsrc, tdst, mss, hacc, efb, sidx, didx);
}

// ---------------- K5: node stats (dtype-independent) ---------------------
__global__ __launch_bounds__(256) void k_node_stats(const float* __restrict__ hacc,
                                                    float* __restrict__ nstats)
{
    __shared__ float red[512];
    const int t = threadIdx.x;
    const int c = t & 63;
    const int rg = t >> 6;
    float s = 0.f, q = 0.f;
    for (int base = blockIdx.x * 4; base < NNODES; base += gridDim.x * 4) {
        const float v = hacc[(size_t)(base + rg) * 64 + c];
        s += v; q += v * v;
    }
    red[t] = s; red[256 + t] = q;
    __syncthreads();
    if (t < 64) {
        float a = 0.f, b = 0.f;
        for (int g = 0; g < 4; ++g) { a += red[g * 64 + t]; b += red[256 + g * 64 + t]; }
        atomicAdd(&nstats[t], a);
        atomicAdd(&nstats[64 + t], b);
    }
}

// ---------------- K6: finalize n-BN -------------------------------------
template <class T>
__device__ __forceinline__ void fin_n_body(const float* nstats, const void* gamma,
                                           const void* beta, float* nss)
{
    const int c = threadIdx.x;  // 64
    const float inv = 1.0f / (float)NNODES;
    const float mean = nstats[c] * inv;
    const float var = fmaxf(nstats[64 + c] * inv - mean * mean, 0.0f);
    const float sc = LD<T>::ld(gamma, c) * rsqrtf(var + BN_EPS);
    nss[c] = sc;
    nss[64 + c] = LD<T>::ld(beta, c) - mean * sc;
}

__global__ void k_fin_n(const float* nstats, const void* gamma, const void* beta,
                        float* nss, const int* flag)
{
    if (*flag) fin_n_body<TF>(nstats, gamma, beta, nss);
    else       fin_n_body<TB>(nstats, gamma, beta, nss);
}

// ---------------- K7: output --------------------------------------------
template <class T>
__device__ __forceinline__ void out_body(const void* node, const float* hacc,
                                         const float* nss, void* out)
{
    const int t = threadIdx.x;
    const int64_t npairs = (int64_t)NNODES * 32;
    int64_t i = (int64_t)blockIdx.x * 256 + t;
    const int c0 = (int)((i * 2) & 63);  // stride is a multiple of 64 elements
    const float sc0 = nss[c0], sh0 = nss[64 + c0];
    const float sc1 = nss[c0 + 1], sh1 = nss[64 + c0 + 1];
    const float2* hp = (const float2*)hacc;
    const int64_t stride = (int64_t)gridDim.x * 256;
    for (; i < npairs; i += stride) {
        const float2 nv = LD<T>::ld2(node, (size_t)(2 * i));
        const float2 h = hp[i];
        const float v0 = softp(nv.x + fmaf(h.x, sc0, sh0));
        const float v1 = softp(nv.y + fmaf(h.y, sc1, sh1));
        LD<T>::st2(out, (size_t)(2 * i), v0, v1);
    }
}

__global__ __launch_bounds__(256) void k_out(const void* node, const float* hacc,
                                             const float* nss, void* out, const int* flag)
{
    if (*flag) out_body<TF>(node, hacc, nss, out);
    else       out_body<TB>(node, hacc, nss, out);
}

extern "C" void kernel_launch(void* const* d_in, const int* in_sizes, int n_in,
                              void* d_out, int out_size, void* d_ws, size_t ws_size,
                              hipStream_t stream)
{
    const void* node = d_in[0];
    const void* ef   = d_in[1];
    const void* Wsrc = d_in[2];
    const void* bsrc = d_in[3];
    const void* Wdst = d_in[4];
    const void* bdst = d_in[5];
    const void* We   = d_in[6];
    const void* be   = d_in[7];
    const void* gm   = d_in[8];
    const void* bm   = d_in[9];
    const void* gn   = d_in[10];
    const void* bn   = d_in[11];
    const int* src   = (const int*)d_in[12];
    const int* dst   = (const int*)d_in[13];

    // ws: hacc(N*64 f32) | mstats(256) | nstats(128) | mss(256) | nss(128) | flag(4 ints) | tsrc | tdst
    float* hacc   = (float*)d_ws;
    float* mstats = hacc + (size_t)NNODES * 64;
    float* nstats = mstats + 256;
    float* mss    = nstats + 128;
    float* nss    = mss + 256;
    int* flag     = (int*)(nss + 128);
    bf16* tsrc    = (bf16*)(flag + 4);
    bf16* tdst    = tsrc + (size_t)NNODES * C2;

    hipMemsetAsync(d_ws, 0, ((size_t)NNODES * 64 + 384) * sizeof(float), stream);
    k_detect<<<1, 256, 0, stream>>>((const uint32_t*)node, flag);
    k_tables<<<512, 256, 0, stream>>>(node, Wsrc, bsrc, Wdst, bdst, tsrc, tdst, flag);
    k_edge_stats<<<2048, 256, 0, stream>>>(ef, src, dst, We, be,
                                           (const uint32_t*)tsrc, (const uint32_t*)tdst,
                                           mstats, flag);
    k_fin_m<<<1, 128, 0, stream>>>(mstats, gm, bm, mss, flag);
    k_edge_apply<<<2048, 256, 0, stream>>>(ef, src, dst, We, be,
                                           (const uint32_t*)tsrc, (const uint32_t*)tdst,
                                           mss, hacc, flag);
    k_node_stats<<<512, 256, 0, stream>>>(hacc, nstats);
    k_fin_n<<<1, 64, 0, stream>>>(nstats, gn, bn, nss, flag);
    k_out<<<1024, 256, 0, stream>>>(node, hacc, nss, d_out, flag);
}

// Round 3
// 1140.337 us; speedup vs baseline: 1.0452x; 1.0452x over previous
//
#include <hip/hip_runtime.h>
#include <hip/hip_bf16.h>
#include <stdint.h>

#define NNODES 100000
#define NEDGES 1600000
#define C2 128
#define EFEAT 32
#define BN_EPS 1e-5f
#define CH 32

typedef __hip_bfloat16 bf16;

__device__ __forceinline__ float bflo(uint32_t u) { return __uint_as_float(u << 16); }
__device__ __forceinline__ float bfhi(uint32_t u) { return __uint_as_float(u & 0xffff0000u); }
__device__ __forceinline__ float sigm(float x) { return 1.0f / (1.0f + __expf(-x)); }
__device__ __forceinline__ float softp(float x) { return fmaxf(x, 0.0f) + log1pf(__expf(-fabsf(x))); }

struct TB {};  // tensors are bf16
struct TF {};  // tensors are fp32

template <class T> struct LD;
template <> struct LD<TB> {
    static __device__ __forceinline__ float ld(const void* p, size_t i) {
        return __bfloat162float(((const bf16*)p)[i]);
    }
    static __device__ __forceinline__ float2 ld2(const void* p, size_t i) {
        const uint32_t u = *(const uint32_t*)((const bf16*)p + i);
        return make_float2(bflo(u), bfhi(u));
    }
    static __device__ __forceinline__ float4 ld4(const void* p, size_t i) {
        const uint2 v = *(const uint2*)((const bf16*)p + i);
        return make_float4(bflo(v.x), bfhi(v.x), bflo(v.y), bfhi(v.y));
    }
    static __device__ __forceinline__ void st2(void* p, size_t i, float a, float b) {
        union { bf16 h[2]; uint32_t u; } pk;
        pk.h[0] = __float2bfloat16(a);
        pk.h[1] = __float2bfloat16(b);
        *(uint32_t*)((bf16*)p + i) = pk.u;
    }
};
template <> struct LD<TF> {
    static __device__ __forceinline__ float ld(const void* p, size_t i) {
        return ((const float*)p)[i];
    }
    static __device__ __forceinline__ float2 ld2(const void* p, size_t i) {
        return *(const float2*)((const float*)p + i);
    }
    static __device__ __forceinline__ float4 ld4(const void* p, size_t i) {
        return *(const float4*)((const float*)p + i);
    }
    static __device__ __forceinline__ void st2(void* p, size_t i, float a, float b) {
        *(float2*)((float*)p + i) = make_float2(a, b);
    }
};

// K0: detect dtype. fp32 data read as packed bf16 has huge low-half values.
__global__ void k_detect(const uint32_t* __restrict__ nodeb, int* __restrict__ flag) {
    __shared__ int sfp;
    if (threadIdx.x == 0) sfp = 0;
    __syncthreads();
    const float v = fabsf(bflo(nodeb[threadIdx.x]));
    if (v > 1e10f) sfp = 1;
    __syncthreads();
    if (threadIdx.x == 0) *flag = sfp;
}

// ---------------- K1: per-node tables -----------------------------------
// h_src = node@Wsrc+bsrc, h_dst = node@Wdst+bdst; stored bf16 pair-interleaved:
// dword j of a row = (col j | col j+64 << 16)
template <class T>
__device__ __forceinline__ void tables_body(
    const void* node, const void* Wsrc, const void* bsrc,
    const void* Wdst, const void* bdst, bf16* tsrc, bf16* tdst, float* x)
{
    const int t = threadIdx.x;
    const int col = t & 127;
    const void* W = (t < 128) ? Wsrc : Wdst;
    float w[64];
#pragma unroll
    for (int k = 0; k < 64; ++k) w[k] = LD<T>::ld(W, k * C2 + col);
    const float b = (t < 128) ? LD<T>::ld(bsrc, col) : LD<T>::ld(bdst, col);
    bf16* tab = (t < 128) ? tsrc : tdst;
    const int pos = (col < 64) ? (2 * col) : (2 * col - 127);
    for (int base = blockIdx.x * 4; base < NNODES; base += gridDim.x * 4) {
        x[t] = LD<T>::ld(node, (size_t)base * 64 + t);
        __syncthreads();
        float a0 = b, a1 = b, a2 = b, a3 = b;
#pragma unroll
        for (int k = 0; k < 64; ++k) {
            const float wv = w[k];
            a0 = fmaf(x[k], wv, a0);
            a1 = fmaf(x[64 + k], wv, a1);
            a2 = fmaf(x[128 + k], wv, a2);
            a3 = fmaf(x[192 + k], wv, a3);
        }
        __syncthreads();
        tab[(size_t)(base + 0) * C2 + pos] = __float2bfloat16(a0);
        tab[(size_t)(base + 1) * C2 + pos] = __float2bfloat16(a1);
        tab[(size_t)(base + 2) * C2 + pos] = __float2bfloat16(a2);
        tab[(size_t)(base + 3) * C2 + pos] = __float2bfloat16(a3);
    }
}

// launch_bounds (256,4): 4 blocks/CU -> 128-VGPR cap so the 64 per-thread
// weight floats stay register-resident (at (256,8)/64 VGPR the compiler
// re-loads We inside the hot loop -> VALU-issue bound, R2 evidence).
__global__ __launch_bounds__(256, 4) void k_tables(
    const void* node, const void* Wsrc, const void* bsrc,
    const void* Wdst, const void* bdst, bf16* tsrc, bf16* tdst, const int* flag)
{
    __shared__ float x[256];
    if (*flag) tables_body<TF>(node, Wsrc, bsrc, Wdst, bdst, tsrc, tdst, x);
    else       tables_body<TB>(node, Wsrc, bsrc, Wdst, bdst, tsrc, tdst, x);
}

// ---------------- K2: edge stats ----------------------------------------
template <class T>
__device__ __forceinline__ void edge_stats_body(
    const void* ef, const int* src, const int* dst, const void* We, const void* be,
    const uint32_t* tsrc, const uint32_t* tdst, float* mstats,
    float* efb, int* sidx, int* didx, float* red)
{
    const int t = threadIdx.x;
    const int c = t & 63;
    const int eg = t >> 6;
    float w0[EFEAT], w1[EFEAT];
#pragma unroll
    for (int k = 0; k < EFEAT; ++k) {
        w0[k] = LD<T>::ld(We, k * C2 + c);
        w1[k] = LD<T>::ld(We, k * C2 + c + 64);
    }
    const float be0 = LD<T>::ld(be, c), be1 = LD<T>::ld(be, c + 64);
    float s0 = 0.f, q0 = 0.f, s1 = 0.f, q1 = 0.f;
    for (int chunk = blockIdx.x * CH; chunk < NEDGES; chunk += gridDim.x * CH) {
        ((float4*)efb)[t] = LD<T>::ld4(ef, (size_t)chunk * EFEAT + 4 * t);
        if (t < CH) sidx[t] = src[chunk + t];
        else if (t < 2 * CH) didx[t - CH] = dst[chunk + t - CH];
        __syncthreads();
        for (int e0 = 0; e0 < CH; e0 += 4) {
            const int e = e0 + eg;
            const int s = sidx[e], d = didx[e];
            float el0 = be0, el1 = be1;
            const float4* efv = (const float4*)(efb + e * EFEAT);
#pragma unroll
            for (int k4 = 0; k4 < EFEAT / 4; ++k4) {
                const float4 f = efv[k4];
                el0 = fmaf(f.x, w0[4 * k4 + 0], el0); el1 = fmaf(f.x, w1[4 * k4 + 0], el1);
                el0 = fmaf(f.y, w0[4 * k4 + 1], el0); el1 = fmaf(f.y, w1[4 * k4 + 1], el1);
                el0 = fmaf(f.z, w0[4 * k4 + 2], el0); el1 = fmaf(f.z, w1[4 * k4 + 2], el1);
                el0 = fmaf(f.w, w0[4 * k4 + 3], el0); el1 = fmaf(f.w, w1[4 * k4 + 3], el1);
            }
            const uint32_t us = tsrc[(size_t)s * 64 + c];
            const uint32_t ud = tdst[(size_t)d * 64 + c];
            const float m0 = el0 + bflo(us) + bflo(ud);
            const float m1 = el1 + bfhi(us) + bfhi(ud);
            s0 += m0; q0 += m0 * m0;
            s1 += m1; q1 += m1 * m1;
        }
        __syncthreads();
    }
    ((float4*)red)[t] = make_float4(s0, q0, s1, q1);
    __syncthreads();
    if (t < 64) {
        float a0 = 0.f, a1 = 0.f, a2 = 0.f, a3 = 0.f;
        for (int g = 0; g < 4; ++g) {
            const float4 r = ((const float4*)red)[g * 64 + t];
            a0 += r.x; a1 += r.y; a2 += r.z; a3 += r.w;
        }
        atomicAdd(&mstats[t], a0);
        atomicAdd(&mstats[C2 + t], a1);
        atomicAdd(&mstats[t + 64], a2);
        atomicAdd(&mstats[C2 + t + 64], a3);
    }
}

__global__ __launch_bounds__(256, 4) void k_edge_stats(
    const void* ef, const int* src, const int* dst, const void* We, const void* be,
    const uint32_t* tsrc, const uint32_t* tdst, float* mstats, const int* flag)
{
    __shared__ float efb[CH * EFEAT];
    __shared__ int sidx[CH], didx[CH];
    __shared__ float red[1024];
    if (*flag) edge_stats_body<TF>(ef, src, dst, We, be, tsrc, tdst, mstats, efb, sidx, didx, red);
    else       edge_stats_body<TB>(ef, src, dst, We, be, tsrc, tdst, mstats, efb, sidx, didx, red);
}

// ---------------- K3: finalize m-BN -------------------------------------
template <class T>
__device__ __forceinline__ void fin_m_body(const float* mstats, const void* gamma,
                                           const void* beta, float* mss)
{
    const int c = threadIdx.x;  // 128
    const float inv = 1.0f / (float)NEDGES;
    const float mean = mstats[c] * inv;
    const float var = fmaxf(mstats[C2 + c] * inv - mean * mean, 0.0f);
    const float sc = LD<T>::ld(gamma, c) * rsqrtf(var + BN_EPS);
    mss[c] = sc;
    mss[C2 + c] = LD<T>::ld(beta, c) - mean * sc;
}

__global__ void k_fin_m(const float* mstats, const void* gamma, const void* beta,
                        float* mss, const int* flag)
{
    if (*flag) fin_m_body<TF>(mstats, gamma, beta, mss);
    else       fin_m_body<TB>(mstats, gamma, beta, mss);
}

// ---------------- K4: edge apply (gate + scatter) ------------------------
template <class T>
__device__ __forceinline__ void edge_apply_body(
    const void* ef, const int* src, const int* dst, const void* We, const void* be,
    const uint32_t* tsrc, const uint32_t* tdst, const float* mss, float* hacc,
    float* efb, int* sidx, int* didx)
{
    const int t = threadIdx.x;
    const int c = t & 63;
    const int eg = t >> 6;
    float w0[EFEAT], w1[EFEAT];
#pragma unroll
    for (int k = 0; k < EFEAT; ++k) {
        w0[k] = LD<T>::ld(We, k * C2 + c);
        w1[k] = LD<T>::ld(We, k * C2 + c + 64);
    }
    const float be0 = LD<T>::ld(be, c), be1 = LD<T>::ld(be, c + 64);
    const float sc0 = mss[c], sh0 = mss[C2 + c];
    const float sc1 = mss[c + 64], sh1 = mss[C2 + c + 64];
    for (int chunk = blockIdx.x * CH; chunk < NEDGES; chunk += gridDim.x * CH) {
        ((float4*)efb)[t] = LD<T>::ld4(ef, (size_t)chunk * EFEAT + 4 * t);
        if (t < CH) sidx[t] = src[chunk + t];
        else if (t < 2 * CH) didx[t - CH] = dst[chunk + t - CH];
        __syncthreads();
        for (int e0 = 0; e0 < CH; e0 += 4) {
            const int e = e0 + eg;
            const int s = sidx[e], d = didx[e];
            float el0 = be0, el1 = be1;
            const float4* efv = (const float4*)(efb + e * EFEAT);
#pragma unroll
            for (int k4 = 0; k4 < EFEAT / 4; ++k4) {
                const float4 f = efv[k4];
                el0 = fmaf(f.x, w0[4 * k4 + 0], el0); el1 = fmaf(f.x, w1[4 * k4 + 0], el1);
                el0 = fmaf(f.y, w0[4 * k4 + 1], el0); el1 = fmaf(f.y, w1[4 * k4 + 1], el1);
                el0 = fmaf(f.z, w0[4 * k4 + 2], el0); el1 = fmaf(f.z, w1[4 * k4 + 2], el1);
                el0 = fmaf(f.w, w0[4 * k4 + 3], el0); el1 = fmaf(f.w, w1[4 * k4 + 3], el1);
            }
            const uint32_t us = tsrc[(size_t)s * 64 + c];
            const uint32_t ud = tdst[(size_t)d * 64 + c];
            const float m0 = el0 + bflo(us) + bflo(ud);
            const float m1 = el1 + bfhi(us) + bfhi(ud);
            const float g = sigm(fmaf(m0, sc0, sh0)) * softp(fmaf(m1, sc1, sh1));
            atomicAdd(&hacc[(size_t)d * 64 + c], g);
        }
        __syncthreads();
    }
}

__global__ __launch_bounds__(256, 4) void k_edge_apply(
    const void* ef, const int* src, const int* dst, const void* We, const void* be,
    const uint32_t* tsrc, const uint32_t* tdst, const float* mss, float* hacc,
    const int* flag)
{
    __shared__ float efb[CH * EFEAT];
    __shared__ int sidx[CH], didx[CH];
    if (*flag) edge_apply_body<TF>(ef, src, dst, We, be, tsrc, tdst, mss, hacc, efb, sidx, didx);
    else       edge_apply_body<TB>(ef, src, dst, We, be, tsrc, tdst, mss, hacc, efb, sidx, didx);
}

// ---------------- K5: node stats (dtype-independent) ---------------------
__global__ __launch_bounds__(256) void k_node_stats(const float* __restrict__ hacc,
                                                    float* __restrict__ nstats)
{
    __shared__ float red[512];
    const int t = threadIdx.x;
    const int c = t & 63;
    const int rg = t >> 6;
    float s = 0.f, q = 0.f;
    for (int base = blockIdx.x * 4; base < NNODES; base += gridDim.x * 4) {
        const float v = hacc[(size_t)(base + rg) * 64 + c];
        s += v; q += v * v;
    }
    red[t] = s; red[256 + t] = q;
    __syncthreads();
    if (t < 64) {
        float a = 0.f, b = 0.f;
        for (int g = 0; g < 4; ++g) { a += red[g * 64 + t]; b += red[256 + g * 64 + t]; }
        atomicAdd(&nstats[t], a);
        atomicAdd(&nstats[64 + t], b);
    }
}

// ---------------- K6: finalize n-BN -------------------------------------
template <class T>
__device__ __forceinline__ void fin_n_body(const float* nstats, const void* gamma,
                                           const void* beta, float* nss)
{
    const int c = threadIdx.x;  // 64
    const float inv = 1.0f / (float)NNODES;
    const float mean = nstats[c] * inv;
    const float var = fmaxf(nstats[64 + c] * inv - mean * mean, 0.0f);
    const float sc = LD<T>::ld(gamma, c) * rsqrtf(var + BN_EPS);
    nss[c] = sc;
    nss[64 + c] = LD<T>::ld(beta, c) - mean * sc;
}

__global__ void k_fin_n(const float* nstats, const void* gamma, const void* beta,
                        float* nss, const int* flag)
{
    if (*flag) fin_n_body<TF>(nstats, gamma, beta, nss);
    else       fin_n_body<TB>(nstats, gamma, beta, nss);
}

// ---------------- K7: output --------------------------------------------
template <class T>
__device__ __forceinline__ void out_body(const void* node, const float* hacc,
                                         const float* nss, void* out)
{
    const int t = threadIdx.x;
    const int64_t npairs = (int64_t)NNODES * 32;
    int64_t i = (int64_t)blockIdx.x * 256 + t;
    const int c0 = (int)((i * 2) & 63);  // stride is a multiple of 64 elements
    const float sc0 = nss[c0], sh0 = nss[64 + c0];
    const float sc1 = nss[c0 + 1], sh1 = nss[64 + c0 + 1];
    const float2* hp = (const float2*)hacc;
    const int64_t stride = (int64_t)gridDim.x * 256;
    for (; i < npairs; i += stride) {
        const float2 nv = LD<T>::ld2(node, (size_t)(2 * i));
        const float2 h = hp[i];
        const float v0 = softp(nv.x + fmaf(h.x, sc0, sh0));
        const float v1 = softp(nv.y + fmaf(h.y, sc1, sh1));
        LD<T>::st2(out, (size_t)(2 * i), v0, v1);
    }
}

__global__ __launch_bounds__(256) void k_out(const void* node, const float* hacc,
                                             const float* nss, void* out, const int* flag)
{
    if (*flag) out_body<TF>(node, hacc, nss, out);
    else       out_body<TB>(node, hacc, nss, out);
}

extern "C" void kernel_launch(void* const* d_in, const int* in_sizes, int n_in,
                              void* d_out, int out_size, void* d_ws, size_t ws_size,
                              hipStream_t stream)
{
    const void* node = d_in[0];
    const void* ef   = d_in[1];
    const void* Wsrc = d_in[2];
    const void* bsrc = d_in[3];
    const void* Wdst = d_in[4];
    const void* bdst = d_in[5];
    const void* We   = d_in[6];
    const void* be   = d_in[7];
    const void* gm   = d_in[8];
    const void* bm   = d_in[9];
    const void* gn   = d_in[10];
    const void* bn   = d_in[11];
    const int* src   = (const int*)d_in[12];
    const int* dst   = (const int*)d_in[13];

    // ws: hacc(N*64 f32) | mstats(256) | nstats(128) | mss(256) | nss(128) | flag(4 ints) | tsrc | tdst
    float* hacc   = (float*)d_ws;
    float* mstats = hacc + (size_t)NNODES * 64;
    float* nstats = mstats + 256;
    float* mss    = nstats + 128;
    float* nss    = mss + 256;
    int* flag     = (int*)(nss + 128);
    bf16* tsrc    = (bf16*)(flag + 4);
    bf16* tdst    = tsrc + (size_t)NNODES * C2;

    hipMemsetAsync(d_ws, 0, ((size_t)NNODES * 64 + 384) * sizeof(float), stream);
    k_detect<<<1, 256, 0, stream>>>((const uint32_t*)node, flag);
    k_tables<<<512, 256, 0, stream>>>(node, Wsrc, bsrc, Wdst, bdst, tsrc, tdst, flag);
    k_edge_stats<<<2048, 256, 0, stream>>>(ef, src, dst, We, be,
                                           (const uint32_t*)tsrc, (const uint32_t*)tdst,
                                           mstats, flag);
    k_fin_m<<<1, 128, 0, stream>>>(mstats, gm, bm, mss, flag);
    k_edge_apply<<<2048, 256, 0, stream>>>(ef, src, dst, We, be,
                                           (const uint32_t*)tsrc, (const uint32_t*)tdst,
                                           mss, hacc, flag);
    k_node_stats<<<512, 256, 0, stream>>>(hacc, nstats);
    k_fin_n<<<1, 64, 0, stream>>>(nstats, gn, bn, nss, flag);
    k_out<<<1024, 256, 0, stream>>>(node, hacc, nss, d_out, flag);
}